// Round 5
// baseline (485.230 us; speedup 1.0000x reference)
//
#include <hip/hip_runtime.h>
#include <stdint.h>

#define NN   100000
#define NE   1600000
#define NG   512
#define HID  128
#define NOUT 64
#define SCAN_B 1024
#define NB   ((NN + SCAN_B - 1) / SCAN_B)   // 98 scan blocks

typedef __bf16 bf16_t;
typedef bf16_t bf16x8 __attribute__((ext_vector_type(8)));
typedef float  f32x4  __attribute__((ext_vector_type(4)));
typedef unsigned int u32;
typedef u32 u32x4 __attribute__((ext_vector_type(4)));
typedef unsigned short u16;

__device__ __forceinline__ u16 f2b(float f) {
    union { float f; u32 u; } v; v.f = f;
    u32 u = v.u + 0x7fffu + ((v.u >> 16) & 1u);   // RNE
    return (u16)(u >> 16);
}
__device__ __forceinline__ float blo(u32 u) {
    union { u32 u; float f; } v; v.u = u << 16; return v.f;
}
__device__ __forceinline__ float bhi(u32 u) {
    union { u32 u; float f; } v; v.u = u & 0xffff0000u; return v.f;
}

// ---------------- CSR build ----------------
__global__ void k_hist(const int* __restrict__ dst, int* __restrict__ cnt) {
    int i = blockIdx.x * blockDim.x + threadIdx.x;
    if (i < NE) atomicAdd(&cnt[dst[i]], 1);
}

// scan1: block-local exclusive scan of cnt -> rp, block sums -> bsum,
// plus fused dinv = rsqrt(cnt+1) and per-graph node counts.
__global__ __launch_bounds__(256) void k_scan1(const int* __restrict__ cnt,
                                               const int* __restrict__ batch,
                                               int* __restrict__ rp, int* __restrict__ bsum,
                                               float* __restrict__ dinv, int* __restrict__ cntg) {
    __shared__ int sh[256];
    int b = blockIdx.x, t = threadIdx.x;
    int base = b * SCAN_B + t * 4;
    int v[4]; int s = 0;
#pragma unroll
    for (int j = 0; j < 4; j++) { int idx = base + j; v[j] = (idx < NN) ? cnt[idx] : 0; s += v[j]; }
    sh[t] = s; __syncthreads();
    for (int off = 1; off < 256; off <<= 1) {
        int x = (t >= off) ? sh[t - off] : 0;
        __syncthreads();
        sh[t] += x;
        __syncthreads();
    }
    if (t == 255) bsum[b] = sh[255];
    int run = sh[t] - s;
#pragma unroll
    for (int j = 0; j < 4; j++) {
        int idx = base + j;
        if (idx < NN) {
            rp[idx] = run;
            dinv[idx] = rsqrtf((float)(v[j] + 1));
            atomicAdd(&cntg[batch[idx]], 1);
        }
        run += v[j];
    }
}

__global__ __launch_bounds__(128) void k_scan2(const int* __restrict__ bsum,
                                               int* __restrict__ boff, int* __restrict__ rpN) {
    __shared__ int sh[128];
    int t = threadIdx.x;
    int v = (t < NB) ? bsum[t] : 0;
    sh[t] = v; __syncthreads();
    for (int off = 1; off < 128; off <<= 1) {
        int x = (t >= off) ? sh[t - off] : 0;
        __syncthreads();
        sh[t] += x;
        __syncthreads();
    }
    if (t < NB) boff[t] = sh[t] - v;
    if (t == 127) rpN[0] = sh[127];   // == NE
}

__global__ void k_scan3(int* __restrict__ rp, const int* __restrict__ boff,
                        int* __restrict__ rp2) {
    int i = blockIdx.x * blockDim.x + threadIdx.x;
    if (i < NN) { int r = rp[i] + boff[i / SCAN_B]; rp[i] = r; rp2[i] = r; }
}

// fill: atomic slot allocation directly on rp2 (returns position)
__global__ void k_fill(const int* __restrict__ src, const int* __restrict__ dst,
                       int* __restrict__ rp2, int* __restrict__ col) {
    int e = blockIdx.x * blockDim.x + threadIdx.x;
    if (e < NE) {
        int d = dst[e];
        int pos = atomicAdd(&rp2[d], 1);
        col[pos] = src[e];
    }
}

// ---------------- weight pack (fragment order, contiguous-output permutation) ----
// Frag f=c*4+s, lane l holds B[k][n]: n_global = (l&15)*8 + c  (so lane's 8 output
// cols are contiguous), k = s*32 + (l>>4)*8 + j.  Packs both W1 and W2.
__global__ void k_pack(const float* __restrict__ W1, const float* __restrict__ W2,
                       u16* __restrict__ Wp1, u16* __restrict__ Wp2) {
    int tid = blockIdx.x * blockDim.x + threadIdx.x;
    if (tid >= 2 * 32 * 64) return;
    const float* W = (tid < 2048) ? W1 : W2;
    u16* Wp = (tid < 2048) ? Wp1 : Wp2;
    int t = tid & 2047;
    int f = t >> 6, l = t & 63;
    int c = f >> 2, s = f & 3;
    int n  = (l & 15) * 8 + c;
    int k0 = s * 32 + ((l >> 4) << 3);
#pragma unroll
    for (int j = 0; j < 8; j++) Wp[t * 8 + j] = f2b(W[(k0 + j) * HID + n]);
}

// ---------------- GEMM: h = X @ W, g = bf16(h * dinv[row]), dwordx4 stores ------
template<int INF32>
__global__ __launch_bounds__(256) void k_gemm(const void* __restrict__ Xin,
                                              const u16* __restrict__ Wp,
                                              const float* __restrict__ dinv,
                                              u16* __restrict__ Gout) {
    int w = threadIdx.x >> 6, l = threadIdx.x & 63;
    int r0  = blockIdx.x * 64 + w * 16;
    int l15 = l & 15, lh = l >> 4;
    int arow = r0 + l15;
    int arc  = (arow < NN) ? arow : (NN - 1);

    const float* Xf = (const float*)Xin;
    const u16*   Xh = (const u16*)Xin;

    f32x4 acc[8];
#pragma unroll
    for (int c = 0; c < 8; c++) acc[c] = (f32x4){0.f, 0.f, 0.f, 0.f};

#pragma unroll
    for (int s = 0; s < 4; s++) {
        int k0 = s * 32 + lh * 8;
        bf16x8 a;
        if (INF32) {
            f32x4 p0 = *(const f32x4*)(Xf + (size_t)arc * HID + k0);
            f32x4 p1 = *(const f32x4*)(Xf + (size_t)arc * HID + k0 + 4);
            union { bf16x8 v; u16 h[8]; } au;
#pragma unroll
            for (int j = 0; j < 4; j++) { au.h[j] = f2b(p0[j]); au.h[j + 4] = f2b(p1[j]); }
            a = au.v;
        } else {
            a = *(const bf16x8*)(Xh + (size_t)arc * HID + k0);
        }
#pragma unroll
        for (int c = 0; c < 8; c++) {
            bf16x8 b = *(const bf16x8*)(Wp + ((c * 4 + s) * 64 + l) * 8);
            acc[c] = __builtin_amdgcn_mfma_f32_16x16x32_bf16(a, b, acc[c], 0, 0, 0);
        }
    }
    // lane l15 owns global cols [8*l15, 8*l15+8) of row r0+lh*4+q -> 16B store
#pragma unroll
    for (int q = 0; q < 4; q++) {
        int row = r0 + lh * 4 + q;
        if (row < NN) {
            float dv = dinv[row];
            union { u32x4 v; u16 h[8]; } pk;
#pragma unroll
            for (int c = 0; c < 8; c++) pk.h[c] = f2b(acc[c][q] * dv);
            *(u32x4*)(Gout + (size_t)row * HID + l15 * 8) = pk.v;
        }
    }
}

// ---------------- aggregation: one wave per node, lane owns 2 features ----------
// One u32 load per lane per row (64 lanes x 4B = full 256B row, coalesced).
// 16 independent rows in flight; full-line packed store via shfl.
template<int LAYER>
__global__ __launch_bounds__(256) void k_agg(const u16* __restrict__ g,
                                             const int* __restrict__ rp,
                                             const int* __restrict__ col,
                                             const float* __restrict__ dinv,
                                             const float* __restrict__ bias,
                                             u16* __restrict__ tout,
                                             const int* __restrict__ batch,
                                             float* __restrict__ psum) {
    int w = threadIdx.x >> 6, l = threadIdx.x & 63;
    int v = blockIdx.x * 4 + w;
    if (v >= NN) return;
    int f0 = 2 * l;
    const u16* gl = g + f0;   // this lane's 4B column within any row

    // self loop: g[v]
    u32 u = *(const u32*)(gl + (size_t)v * HID);
    float a0 = blo(u), a1 = bhi(u);

    int e = rp[v], end = rp[v + 1];
    while (e < end) {
        int m = end - e; if (m > 64) m = 64;
        int ci = col[e + ((l < m) ? l : 0)];
        int j = 0;
        for (; j + 16 <= m; j += 16) {
            u32 uu[16];
#pragma unroll
            for (int k = 0; k < 16; k++) {
                int idx = __shfl(ci, j + k);
                uu[k] = *(const u32*)(gl + (size_t)idx * HID);
            }
#pragma unroll
            for (int k = 0; k < 16; k++) { a0 += blo(uu[k]); a1 += bhi(uu[k]); }
        }
        for (; j + 4 <= m; j += 4) {
            u32 uu[4];
#pragma unroll
            for (int k = 0; k < 4; k++) {
                int idx = __shfl(ci, j + k);
                uu[k] = *(const u32*)(gl + (size_t)idx * HID);
            }
#pragma unroll
            for (int k = 0; k < 4; k++) { a0 += blo(uu[k]); a1 += bhi(uu[k]); }
        }
        if (j < m) {
            int r = m - j;
            u32 uu[3];
#pragma unroll
            for (int k = 0; k < 3; k++) {
                int jk = j + k; int idx = __shfl(ci, (jk < m) ? jk : j);
                uu[k] = *(const u32*)(gl + (size_t)idx * HID);
            }
#pragma unroll
            for (int k = 0; k < 3; k++) {
                float mk = (k < r) ? 1.f : 0.f;
                a0 = fmaf(mk, blo(uu[k]), a0); a1 = fmaf(mk, bhi(uu[k]), a1);
            }
        }
        e += m;
    }

    float dv = dinv[v];
    float o0 = a0 * dv + bias[f0];
    float o1 = a1 * dv + bias[f0 + 1];
    if (LAYER == 1) {
        o0 = fmaxf(o0, 0.f); o1 = fmaxf(o1, 0.f);
        u32 pk = (u32)f2b(o0) | ((u32)f2b(o1) << 16);
        // pack into lanes 0..15, one dwordx4 per lane = full 256B row
        int l15 = l & 15;
        u32 w0 = __shfl(pk, l15 * 4 + 0);
        u32 w1 = __shfl(pk, l15 * 4 + 1);
        u32 w2 = __shfl(pk, l15 * 4 + 2);
        u32 w3 = __shfl(pk, l15 * 4 + 3);
        if (l < 16) {
            u32x4 vv = (u32x4){w0, w1, w2, w3};
            *(u32x4*)(tout + (size_t)v * HID + l * 8) = vv;
        }
    } else {
        int bg = batch[v];
        atomicAdd(&psum[(size_t)bg * HID + f0],     o0);
        atomicAdd(&psum[(size_t)bg * HID + f0 + 1], o1);
    }
}

// ---------------- pooled FC ----------------
__global__ __launch_bounds__(64) void k_fc(const float* __restrict__ psum,
                                           const int* __restrict__ cntg,
                                           const float* __restrict__ Wfc,
                                           const float* __restrict__ bfc,
                                           float* __restrict__ out) {
    __shared__ float pooled[HID];
    int gph = blockIdx.x, t = threadIdx.x;
    float inv = 1.f / fmaxf((float)cntg[gph], 1.f);
    for (int k = t; k < HID; k += 64) pooled[k] = psum[gph * HID + k] * inv;
    __syncthreads();
    float acc = bfc[t];
    for (int k = 0; k < HID; k++) acc += pooled[k] * Wfc[k * NOUT + t];
    out[gph * NOUT + t] = acc;
}

extern "C" void kernel_launch(void* const* d_in, const int* in_sizes, int n_in,
                              void* d_out, int out_size, void* d_ws, size_t ws_size,
                              hipStream_t stream) {
    const float* x     = (const float*)d_in[0];
    const int*   ei    = (const int*)d_in[1];
    const int*   batch = (const int*)d_in[3];
    const float* W1    = (const float*)d_in[4];
    const float* b1    = (const float*)d_in[5];
    const float* W2    = (const float*)d_in[6];
    const float* b2    = (const float*)d_in[7];
    const float* Wfc   = (const float*)d_in[8];
    const float* bfc   = (const float*)d_in[9];
    float* out = (float*)d_out;

    const int* src = ei;
    const int* dst = ei + NE;

    char* p = (char*)d_ws;
    auto take = [&](size_t bytes) { char* r = p; p += (bytes + 255) & ~(size_t)255; return r; };
    int*   cnt  = (int*)take((size_t)NN * 4);
    int*   rp   = (int*)take((size_t)(NN + 1) * 4);
    int*   rp2  = (int*)take((size_t)NN * 4);
    int*   bsum = (int*)take(256 * 4);
    int*   boff = (int*)take(256 * 4);
    float* dinv = (float*)take((size_t)NN * 4);
    int*   cntg = (int*)take((size_t)NG * 4);          // adjacent to psum:
    float* psum = (float*)take((size_t)NG * HID * 4);  // single memset covers both
    u16*   Wp1  = (u16*)take((size_t)32 * 64 * 8 * 2);
    u16*   Wp2  = (u16*)take((size_t)32 * 64 * 8 * 2);
    int*   col  = (int*)take((size_t)NE * 4);
    u16*   g    = (u16*)take((size_t)NN * HID * 2);
    u16*   t    = (u16*)take((size_t)NN * HID * 2);

    hipMemsetAsync(cnt,  0, (size_t)NN * 4, stream);
    hipMemsetAsync(cntg, 0, (size_t)NG * 4 + (size_t)NG * HID * 4, stream);

    k_hist <<<(NE + 255) / 256, 256, 0, stream>>>(dst, cnt);
    k_scan1<<<NB, 256, 0, stream>>>(cnt, batch, rp, bsum, dinv, cntg);
    k_scan2<<<1, 128, 0, stream>>>(bsum, boff, rp + NN);
    k_scan3<<<(NN + 255) / 256, 256, 0, stream>>>(rp, boff, rp2);
    k_fill <<<(NE + 255) / 256, 256, 0, stream>>>(src, dst, rp2, col);
    k_pack <<<16, 256, 0, stream>>>(W1, W2, Wp1, Wp2);

    k_gemm<1><<<(NN + 63) / 64, 256, 0, stream>>>((const void*)x, Wp1, dinv, g);
    k_agg<1> <<<(NN + 3) / 4, 256, 0, stream>>>(g, rp, col, dinv, b1, t, nullptr, nullptr);
    k_gemm<0><<<(NN + 63) / 64, 256, 0, stream>>>((const void*)t, Wp2, dinv, g);
    k_agg<2> <<<(NN + 3) / 4, 256, 0, stream>>>(g, rp, col, dinv, b2, nullptr, batch, psum);
    k_fc   <<<NG, 64, 0, stream>>>(psum, cntg, Wfc, bfc, out);
}

// Round 6
// 341.619 us; speedup vs baseline: 1.4204x; 1.4204x over previous
//
#include <hip/hip_runtime.h>
#include <stdint.h>

#define NN   100000
#define NE   1600000
#define NG   512
#define HID  128
#define NOUT 64
#define BK   512
#define NBUK ((NN + BK - 1) / BK)      // 196 buckets of 512 nodes
#define AHIST_E 4096
#define NAH  ((NE + AHIST_E - 1) / AHIST_E)   // 391
#define CHUNK 8192
#define NSC  ((NE + CHUNK - 1) / CHUNK)       // 196

typedef __bf16 bf16_t;
typedef bf16_t bf16x8 __attribute__((ext_vector_type(8)));
typedef float  f32x4  __attribute__((ext_vector_type(4)));
typedef unsigned int u32;
typedef u32 u32x4 __attribute__((ext_vector_type(4)));
typedef unsigned short u16;

struct __align__(8) EdgeT { int d, s; };

__device__ __forceinline__ u16 f2b(float f) {
    union { float f; u32 u; } v; v.f = f;
    u32 u = v.u + 0x7fffu + ((v.u >> 16) & 1u);   // RNE
    return (u16)(u >> 16);
}
__device__ __forceinline__ float blo(u32 u) {
    union { u32 u; float f; } v; v.u = u << 16; return v.f;
}
__device__ __forceinline__ float bhi(u32 u) {
    union { u32 u; float f; } v; v.u = u & 0xffff0000u; return v.f;
}

// ---------------- CSR build, bucketed ----------------
// Pass A: per-bucket edge histogram (LDS-staged)
__global__ __launch_bounds__(256) void k_bhist(const int* __restrict__ dst,
                                               int* __restrict__ bcnt) {
    __shared__ int h[NBUK];
    int t = threadIdx.x;
    for (int i = t; i < NBUK; i += 256) h[i] = 0;
    __syncthreads();
    int e0 = blockIdx.x * AHIST_E;
    int e1 = min(NE, e0 + AHIST_E);
    for (int e = e0 + t; e < e1; e += 256) atomicAdd(&h[dst[e] >> 9], 1);
    __syncthreads();
    for (int i = t; i < NBUK; i += 256) if (h[i]) atomicAdd(&bcnt[i], h[i]);
}

// Pass B: scan bucket counts -> boff (and gcur working copy); rp[NN]=NE
__global__ __launch_bounds__(256) void k_bscan(const int* __restrict__ bcnt,
                                               int* __restrict__ boff, int* __restrict__ gcur,
                                               int* __restrict__ rp) {
    __shared__ int sh[256];
    int t = threadIdx.x;
    int v = (t < NBUK) ? bcnt[t] : 0;
    sh[t] = v; __syncthreads();
    for (int off = 1; off < 256; off <<= 1) {
        int x = (t >= off) ? sh[t - off] : 0;
        __syncthreads();
        sh[t] += x;
        __syncthreads();
    }
    if (t < NBUK) { int b = sh[t] - v; boff[t] = b; gcur[t] = b; }
    if (t == 0) { boff[NBUK] = NE; rp[NN] = NE; }
}

// Pass C: scatter (dst,src) into bucket-contiguous ebuf (LDS-ranked, coalesced-ish)
__global__ __launch_bounds__(256) void k_scatter(const int* __restrict__ src,
                                                 const int* __restrict__ dst,
                                                 int* __restrict__ gcur,
                                                 EdgeT* __restrict__ ebuf) {
    __shared__ int hist[NBUK], base[NBUK];
    int t = threadIdx.x;
    for (int i = t; i < NBUK; i += 256) hist[i] = 0;
    __syncthreads();
    int e0 = blockIdx.x * CHUNK;
    int e1 = min(NE, e0 + CHUNK);
    for (int e = e0 + t; e < e1; e += 256) atomicAdd(&hist[dst[e] >> 9], 1);
    __syncthreads();
    for (int i = t; i < NBUK; i += 256) {
        int h = hist[i];
        base[i] = h ? atomicAdd(&gcur[i], h) : 0;
        hist[i] = 0;
    }
    __syncthreads();
    for (int e = e0 + t; e < e1; e += 256) {
        int d = dst[e], bk = d >> 9;
        int r = atomicAdd(&hist[bk], 1);
        EdgeT p; p.d = d; p.s = src[e];
        ebuf[base[bk] + r] = p;
    }
}

// Pass D: one block per bucket — per-node count, LDS scan, rp/dinv/cntg, local fill
__global__ __launch_bounds__(256) void k_bucketc(const EdgeT* __restrict__ ebuf,
                                                 const int* __restrict__ boff,
                                                 const int* __restrict__ batch,
                                                 int* __restrict__ rp, float* __restrict__ dinv,
                                                 int* __restrict__ cntg, int* __restrict__ col) {
    __shared__ int cnt[BK], pos[BK], run[BK], s2[256];
    int b = blockIdx.x, t = threadIdx.x;
    int d0 = b * BK;
    int e0 = boff[b], e1 = boff[b + 1];
    for (int i = t; i < BK; i += 256) { cnt[i] = 0; run[i] = 0; }
    __syncthreads();
    for (int e = e0 + t; e < e1; e += 256) atomicAdd(&cnt[ebuf[e].d - d0], 1);
    __syncthreads();
    for (int i = t; i < BK; i += 256) {
        int v = d0 + i;
        if (v < NN) {
            dinv[v] = rsqrtf((float)(cnt[i] + 1));
            atomicAdd(&cntg[batch[v]], 1);
        }
    }
    // exclusive scan of cnt[0..511] with 256 threads (pair-sum)
    int c0 = cnt[2 * t], c1 = cnt[2 * t + 1];
    int s = c0 + c1; s2[t] = s; __syncthreads();
    for (int off = 1; off < 256; off <<= 1) {
        int x = (t >= off) ? s2[t - off] : 0;
        __syncthreads();
        s2[t] += x;
        __syncthreads();
    }
    int bse = s2[t] - s;
    pos[2 * t] = bse; pos[2 * t + 1] = bse + c0;
    __syncthreads();
    for (int i = t; i < BK; i += 256) {
        int v = d0 + i;
        if (v < NN) rp[v] = e0 + pos[i];
    }
    for (int e = e0 + t; e < e1; e += 256) {
        EdgeT p = ebuf[e];
        int i = p.d - d0;
        int r = atomicAdd(&run[i], 1);
        col[e0 + pos[i] + r] = p.s;
    }
}

// ---------------- weight pack (fragment order, contiguous-output permutation) ----
// Frag f=c*4+s, lane l holds B[k][n]: n_global = (l&15)*8 + c, k = s*32+(l>>4)*8+j.
__global__ void k_pack(const float* __restrict__ W, u16* __restrict__ Wp) {
    int tid = blockIdx.x * blockDim.x + threadIdx.x;
    if (tid >= 32 * 64) return;
    int f = tid >> 6, l = tid & 63;
    int c = f >> 2, s = f & 3;
    int n  = (l & 15) * 8 + c;
    int k0 = s * 32 + ((l >> 4) << 3);
#pragma unroll
    for (int j = 0; j < 8; j++) Wp[tid * 8 + j] = f2b(W[(k0 + j) * HID + n]);
}

// Wc = W2 @ Wfc [HID x NOUT], bc = b2 @ Wfc + bfc [NOUT]
__global__ void k_wc(const float* __restrict__ W2, const float* __restrict__ Wfc,
                     const float* __restrict__ b2, const float* __restrict__ bfc,
                     float* __restrict__ Wc, float* __restrict__ bc) {
    int tid = blockIdx.x * blockDim.x + threadIdx.x;
    if (tid < HID * NOUT) {
        int i = tid >> 6, o = tid & 63;
        float a = 0.f;
        for (int k = 0; k < HID; k++) a += W2[i * HID + k] * Wfc[k * NOUT + o];
        Wc[i * NOUT + o] = a;
    }
    if (tid < NOUT) {
        float a = bfc[tid];
        for (int k = 0; k < HID; k++) a += b2[k] * Wfc[k * NOUT + tid];
        bc[tid] = a;
    }
}

// ---------------- GEMM: g = bf16((X @ W1) * dinv[row]), dwordx4 stores ----------
__global__ __launch_bounds__(256) void k_gemm(const float* __restrict__ Xf,
                                              const u16* __restrict__ Wp,
                                              const float* __restrict__ dinv,
                                              u16* __restrict__ Gout) {
    int w = threadIdx.x >> 6, l = threadIdx.x & 63;
    int r0  = blockIdx.x * 64 + w * 16;
    int l15 = l & 15, lh = l >> 4;
    int arow = r0 + l15;
    int arc  = (arow < NN) ? arow : (NN - 1);

    f32x4 acc[8];
#pragma unroll
    for (int c = 0; c < 8; c++) acc[c] = (f32x4){0.f, 0.f, 0.f, 0.f};

#pragma unroll
    for (int s = 0; s < 4; s++) {
        int k0 = s * 32 + lh * 8;
        f32x4 p0 = *(const f32x4*)(Xf + (size_t)arc * HID + k0);
        f32x4 p1 = *(const f32x4*)(Xf + (size_t)arc * HID + k0 + 4);
        union { bf16x8 v; u16 h[8]; } au;
#pragma unroll
        for (int j = 0; j < 4; j++) { au.h[j] = f2b(p0[j]); au.h[j + 4] = f2b(p1[j]); }
        bf16x8 a = au.v;
#pragma unroll
        for (int c = 0; c < 8; c++) {
            bf16x8 b = *(const bf16x8*)(Wp + ((c * 4 + s) * 64 + l) * 8);
            acc[c] = __builtin_amdgcn_mfma_f32_16x16x32_bf16(a, b, acc[c], 0, 0, 0);
        }
    }
#pragma unroll
    for (int q = 0; q < 4; q++) {
        int row = r0 + lh * 4 + q;
        if (row < NN) {
            float dv = dinv[row];
            union { u32x4 v; u16 h[8]; } pk;
#pragma unroll
            for (int c = 0; c < 8; c++) pk.h[c] = f2b(acc[c][q] * dv);
            *(u32x4*)(Gout + (size_t)row * HID + l15 * 8) = pk.v;
        }
    }
}

// ---------------- aggregation: one wave per node, lane owns 2 features ----------
// LAYER 1: T[v] = bf16(dinv[v] * relu(dinv[v]*Sum + b1))   (pre-scaled for layer 2)
// LAYER 2: psum[batch[v]] += dinv[v] * Sum                 (W2/b2 folded into FC)
template<int LAYER>
__global__ __launch_bounds__(256) void k_agg(const u16* __restrict__ g,
                                             const int* __restrict__ rp,
                                             const int* __restrict__ col,
                                             const float* __restrict__ dinv,
                                             const float* __restrict__ bias,
                                             u16* __restrict__ tout,
                                             const int* __restrict__ batch,
                                             float* __restrict__ psum) {
    int w = threadIdx.x >> 6, l = threadIdx.x & 63;
    int v = blockIdx.x * 4 + w;
    if (v >= NN) return;
    int f0 = 2 * l;
    const u16* gl = g + f0;   // this lane's 4B column within any row

    u32 u = *(const u32*)(gl + (size_t)v * HID);   // self loop
    float a0 = blo(u), a1 = bhi(u);

    int e = rp[v], end = rp[v + 1];
    while (e < end) {
        int m = end - e; if (m > 64) m = 64;
        int ci = col[e + ((l < m) ? l : 0)];
        int j = 0;
        for (; j + 16 <= m; j += 16) {
            u32 uu[16];
#pragma unroll
            for (int k = 0; k < 16; k++) {
                int idx = __shfl(ci, j + k);
                uu[k] = *(const u32*)(gl + (size_t)idx * HID);
            }
#pragma unroll
            for (int k = 0; k < 16; k++) { a0 += blo(uu[k]); a1 += bhi(uu[k]); }
        }
        for (; j + 4 <= m; j += 4) {
            u32 uu[4];
#pragma unroll
            for (int k = 0; k < 4; k++) {
                int idx = __shfl(ci, j + k);
                uu[k] = *(const u32*)(gl + (size_t)idx * HID);
            }
#pragma unroll
            for (int k = 0; k < 4; k++) { a0 += blo(uu[k]); a1 += bhi(uu[k]); }
        }
        if (j < m) {
            int r = m - j;
            u32 uu[3];
#pragma unroll
            for (int k = 0; k < 3; k++) {
                int jk = j + k; int idx = __shfl(ci, (jk < m) ? jk : j);
                uu[k] = *(const u32*)(gl + (size_t)idx * HID);
            }
#pragma unroll
            for (int k = 0; k < 3; k++) {
                float mk = (k < r) ? 1.f : 0.f;
                a0 = fmaf(mk, blo(uu[k]), a0); a1 = fmaf(mk, bhi(uu[k]), a1);
            }
        }
        e += m;
    }

    float dv = dinv[v];
    if (LAYER == 1) {
        float o0 = fmaxf(a0 * dv + bias[f0],     0.f) * dv;
        float o1 = fmaxf(a1 * dv + bias[f0 + 1], 0.f) * dv;
        u32 pk = (u32)f2b(o0) | ((u32)f2b(o1) << 16);
        int l15 = l & 15;
        u32 w0 = __shfl(pk, l15 * 4 + 0);
        u32 w1 = __shfl(pk, l15 * 4 + 1);
        u32 w2 = __shfl(pk, l15 * 4 + 2);
        u32 w3 = __shfl(pk, l15 * 4 + 3);
        if (l < 16) {
            u32x4 vv = (u32x4){w0, w1, w2, w3};
            *(u32x4*)(tout + (size_t)v * HID + l * 8) = vv;
        }
    } else {
        int bg = batch[v];
        atomicAdd(&psum[(size_t)bg * HID + f0],     a0 * dv);
        atomicAdd(&psum[(size_t)bg * HID + f0 + 1], a1 * dv);
    }
}

// ---------------- pooled FC: out = (psum/cnt) @ Wc + bc ----------------
__global__ __launch_bounds__(64) void k_fc(const float* __restrict__ psum,
                                           const int* __restrict__ cntg,
                                           const float* __restrict__ Wc,
                                           const float* __restrict__ bc,
                                           float* __restrict__ out) {
    __shared__ float pooled[HID];
    int gph = blockIdx.x, t = threadIdx.x;
    float inv = 1.f / fmaxf((float)cntg[gph], 1.f);
    for (int k = t; k < HID; k += 64) pooled[k] = psum[gph * HID + k] * inv;
    __syncthreads();
    float acc = bc[t];
    for (int k = 0; k < HID; k++) acc += pooled[k] * Wc[k * NOUT + t];
    out[gph * NOUT + t] = acc;
}

extern "C" void kernel_launch(void* const* d_in, const int* in_sizes, int n_in,
                              void* d_out, int out_size, void* d_ws, size_t ws_size,
                              hipStream_t stream) {
    const float* x     = (const float*)d_in[0];
    const int*   ei    = (const int*)d_in[1];
    const int*   batch = (const int*)d_in[3];
    const float* W1    = (const float*)d_in[4];
    const float* b1    = (const float*)d_in[5];
    const float* W2    = (const float*)d_in[6];
    const float* b2    = (const float*)d_in[7];
    const float* Wfc   = (const float*)d_in[8];
    const float* bfc   = (const float*)d_in[9];
    float* out = (float*)d_out;

    const int* src = ei;
    const int* dst = ei + NE;

    char* p = (char*)d_ws;
    auto take = [&](size_t bytes) { char* r = p; p += (bytes + 255) & ~(size_t)255; return r; };
    // zero-group (one memset covers bcnt..psum)
    int*   bcnt = (int*)take((size_t)NBUK * 4);
    int*   cntg = (int*)take((size_t)NG * 4);
    float* psum = (float*)take((size_t)NG * HID * 4);
    size_t zspan = (size_t)((char*)psum + (size_t)NG * HID * 4 - (char*)bcnt);
    // rest
    int*   boff = (int*)take((size_t)(NBUK + 1) * 4);
    int*   gcur = (int*)take((size_t)NBUK * 4);
    int*   rp   = (int*)take((size_t)(NN + 1) * 4);
    float* dinv = (float*)take((size_t)NN * 4);
    u16*   Wp1  = (u16*)take((size_t)32 * 64 * 8 * 2);
    float* Wc   = (float*)take((size_t)HID * NOUT * 4);
    float* bc   = (float*)take((size_t)NOUT * 4);
    int*   col  = (int*)take((size_t)NE * 4);
    u16*   g    = (u16*)take((size_t)NN * HID * 2);
    u16*   t    = (u16*)take((size_t)NN * HID * 2);
    EdgeT* ebuf = (EdgeT*)g;   // aliased: ebuf consumed by k_bucketc before k_gemm writes g

    hipMemsetAsync(bcnt, 0, zspan, stream);

    k_bhist  <<<NAH, 256, 0, stream>>>(dst, bcnt);
    k_bscan  <<<1, 256, 0, stream>>>(bcnt, boff, gcur, rp);
    k_scatter<<<NSC, 256, 0, stream>>>(src, dst, gcur, ebuf);
    k_bucketc<<<NBUK, 256, 0, stream>>>(ebuf, boff, batch, rp, dinv, cntg, col);
    k_pack   <<<8, 256, 0, stream>>>(W1, Wp1);
    k_wc     <<<(HID * NOUT + 255) / 256, 256, 0, stream>>>(W2, Wfc, b2, bfc, Wc, bc);

    k_gemm   <<<(NN + 63) / 64, 256, 0, stream>>>(x, Wp1, dinv, g);
    k_agg<1> <<<(NN + 3) / 4, 256, 0, stream>>>(g, rp, col, dinv, b1, t, nullptr, nullptr);
    k_agg<2> <<<(NN + 3) / 4, 256, 0, stream>>>(t, rp, col, dinv, nullptr, nullptr, batch, psum);
    k_fc     <<<NG, 64, 0, stream>>>(psum, cntg, Wc, bc, out);
}